// Round 11
// baseline (74.234 us; speedup 1.0000x reference)
//
#include <hip/hip_runtime.h>
#include <stdint.h>

#define N_ANCH 65648
#define NCHUNK 65          // chunks of 1024 anchors
#define CHUNK  1024
#define CAP    2048        // per-batch candidate capacity
#define KBASE  0xBE800000u // sortable key of 0.25; fg scores >= 1/3 -> bins in [42,255]
#define NBATCH 32
#define TOPK   100
#define FT     256

struct Ptrs { const float* cls[8]; const float* reg[8]; };

__constant__ int   c_off[9] = {0,25281,50562,56803,63044,64565,64926,65287,65648};
__constant__ int   c_sz[8]  = {159,159,79,79,39,19,19,19};
__constant__ float c_st[8]  = {4.f,4.f,8.f,8.f,16.f,32.f,32.f,32.f};
__constant__ float c_rf[8]  = {27.5f,35.5f,55.5f,71.5f,111.5f,191.5f,255.5f,319.5f};

// sortable key for the masked score of anchor n in batch b; 0 if background.
// EXACT same fp sequence as all passing rounds.
__device__ inline uint32_t anchor_key(const Ptrs& p, int b, int n) {
  int k = 0;
#pragma unroll
  for (int q = 1; q < 8; ++q) if (n >= c_off[q]) k = q;
  int local = n - c_off[k];
  int hw = c_sz[k] * c_sz[k];
  const float* c = p.cls[k] + (size_t)(b * 3) * hw + local;
  float l0 = c[0], l1 = c[(size_t)hw], l2 = c[(size_t)2 * hw];
  float m = l0; int cl = 0;
  if (l1 > m) { m = l1; cl = 1; }
  if (l2 > m) { m = l2; cl = 2; }
  if (cl == 0) return 0u;
  float s = 1.0f / (expf(l0 - m) + expf(l1 - m) + expf(l2 - m));
  return __float_as_uint(s) | 0x80000000u; // positive float -> monotonic uint
}

// K1 (WIDE, 2080 blocks): exact u32 key per anchor (coalesced) + per-chunk u16 hist
__global__ __launch_bounds__(256) void k_keys(Ptrs p, uint32_t* keys, uint16_t* hist) {
  int bid = blockIdx.x;
  int b = bid / NCHUNK, chunk = bid % NCHUNK;
  int t = threadIdx.x;
  __shared__ uint32_t lh[256];
  lh[t] = 0;
  __syncthreads();
  int n_base = chunk * CHUNK;
#pragma unroll
  for (int u = 0; u < 4; ++u) {
    int n = n_base + u * 256 + t;
    if (n < N_ANCH) {
      uint32_t key = anchor_key(p, b, n);
      keys[(size_t)b * N_ANCH + n] = key;
      if (key >= KBASE) atomicAdd(&lh[(key - KBASE) >> 16], 1u);  // LDS only
    }
  }
  __syncthreads();
  hist[((size_t)b * NCHUNK + chunk) * 256 + t] = (uint16_t)lh[t];
}

// K2 (32 blocks): ONE hist reduce per batch -> threshold key; zero counter.
__global__ __launch_bounds__(256) void k_thresh(const uint16_t* hist, uint32_t* thkey,
                                                uint32_t* counter) {
  int b = blockIdx.x, t = threadIdx.x;
  __shared__ uint32_t tot[256];
  __shared__ int s_thr;
  const uint16_t* hb = hist + (size_t)b * NCHUNK * 256;
  uint32_t v0 = 0, v1 = 0, v2 = 0, v3 = 0;
  int ch = 0;
  for (; ch + 4 <= NCHUNK; ch += 4) {          // 4 accumulators: independent loads
    v0 += hb[(ch + 0) * 256 + t];
    v1 += hb[(ch + 1) * 256 + t];
    v2 += hb[(ch + 2) * 256 + t];
    v3 += hb[(ch + 3) * 256 + t];
  }
  for (; ch < NCHUNK; ++ch) v0 += hb[ch * 256 + t];
  tot[t] = v0 + v1 + v2 + v3;
  __syncthreads();
  for (int d = 1; d < 256; d <<= 1) {          // inclusive suffix sum
    uint32_t add = (t + d < 256) ? tot[t + d] : 0u;
    __syncthreads();
    tot[t] += add;
    __syncthreads();
  }
  uint32_t suf = tot[t], sufn = (t < 255) ? tot[t + 1] : 0u;
  if (suf >= TOPK && sufn < TOPK) s_thr = t;   // exactly one setter
  if (t == 0 && tot[0] < TOPK) s_thr = 0;
  __syncthreads();
  if (t == 0) {
    int thr = s_thr; if (thr < 1) thr = 1;     // bin>=1 <=> foreground
    thkey[b] = KBASE + ((uint32_t)thr << 16);
    counter[b] = 0;
  }
}

// K3 (WIDE, 2080 blocks): filter own 1024-key chunk vs thkey[b]; LDS stage;
// ONE global atomic per block; coalesced candidate write.
__global__ __launch_bounds__(256) void k_collect(const uint32_t* keys, const uint32_t* thkey,
                                                 uint32_t* counter, unsigned long long* cand) {
  int bid = blockIdx.x;
  int b = bid / NCHUNK, chunk = bid % NCHUNK;
  int t = threadIdx.x;
  __shared__ unsigned long long stage[CHUNK];
  __shared__ uint32_t s_cnt, s_base;
  if (t == 0) s_cnt = 0;
  __syncthreads();
  uint32_t thk = thkey[b];
  int n0 = chunk * CHUNK + t * 4;
  if (n0 < N_ANCH) {                           // full quads (65648 % 4 == 0)
    uint4 kv = *(const uint4*)(keys + (size_t)b * N_ANCH + n0);
    const uint32_t* kp = (const uint32_t*)&kv;
#pragma unroll
    for (int u = 0; u < 4; ++u) {
      uint32_t key = kp[u];
      if (key >= thk) {
        uint32_t pos = atomicAdd(&s_cnt, 1u);  // LDS; pos < CHUNK always
        stage[pos] = ((unsigned long long)key << 32) | (uint32_t)(~(uint32_t)(n0 + u));
      }
    }
  }
  __syncthreads();
  if (t == 0) s_base = atomicAdd(&counter[b], s_cnt);  // one global atomic per block
  __syncthreads();
  uint32_t cnt = s_cnt, base = s_base;
  for (uint32_t j = t; j < cnt; j += 256) {
    uint32_t g = base + j;
    if (g < CAP) cand[(size_t)b * CAP + g] = stage[j]; // coalesced
  }
}

// rank-selection with 8-deep batched LDS broadcast reads; s_all zero-padded to
// a multiple of 8 (zeros never outrank real keys).
template<int U>
__device__ inline void rank_select(const unsigned long long* s_all, int c, int c8, int t,
                                   unsigned long long* top) {
  unsigned long long mine[U]; int rk[U];
#pragma unroll
  for (int u = 0; u < U; ++u) {
    int i = t + u * FT;
    mine[u] = (i < c) ? s_all[i] : 0ull;
    rk[u] = 0;
  }
  for (int j = 0; j < c8; j += 8) {
    unsigned long long v0 = s_all[j+0], v1 = s_all[j+1], v2 = s_all[j+2], v3 = s_all[j+3];
    unsigned long long v4 = s_all[j+4], v5 = s_all[j+5], v6 = s_all[j+6], v7 = s_all[j+7];
#pragma unroll
    for (int u = 0; u < U; ++u) {
      rk[u] += (v0 > mine[u]) + (v1 > mine[u]) + (v2 > mine[u]) + (v3 > mine[u])
             + (v4 > mine[u]) + (v5 > mine[u]) + (v6 > mine[u]) + (v7 > mine[u]);
    }
  }
#pragma unroll
  for (int u = 0; u < U; ++u) {
    int i = t + u * FT;
    if (i < c && rk[u] < TOPK) top[rk[u]] = mine[u];   // unique u64s -> unique ranks
  }
}

// K4 (32 blocks): strictly O(c): load cands, rank-select, decode, NMS, out.
__global__ __launch_bounds__(FT) void k_final(Ptrs p, const uint32_t* counter,
                                              const unsigned long long* cand, float* out) {
  int b = blockIdx.x, t = threadIdx.x;
  __shared__ unsigned long long s_all[CAP + 8];
  __shared__ unsigned long long top[TOPK];
  __shared__ float bx1[TOPK], by1[TOPK], bx2[TOPK], by2[TOPK], area[TOPK], sc[TOPK];
  __shared__ int cls_s[TOPK], keep[TOPK];

  int c = (int)min(counter[b], (uint32_t)CAP);
  int c8 = (c + 7) & ~7;
  for (int i = t; i < c; i += FT) s_all[i] = cand[(size_t)b * CAP + i]; // coalesced
  for (int i = c + t; i < c8; i += FT) s_all[i] = 0ull;                 // pad
  if (t < TOPK) top[t] = 0ull;
  __syncthreads();

  if      (c <= FT)     rank_select<1>(s_all, c, c8, t, top);
  else if (c <= 2 * FT) rank_select<2>(s_all, c, c8, t, top);
  else if (c <= 4 * FT) rank_select<4>(s_all, c, c8, t, top);
  else                  rank_select<8>(s_all, c, c8, t, top);
  __syncthreads();

  // decode top-100
  int r = t;
  if (r < TOPK) {
    unsigned long long pk = top[r];
    if (pk == 0ull) {
      sc[r] = -1.f; cls_s[r] = 0; keep[r] = 0;
      bx1[r] = by1[r] = bx2[r] = by2[r] = 0.f; area[r] = 1.f;
    } else {
      uint32_t key = (uint32_t)(pk >> 32);
      int n = (int)(~(uint32_t)pk);
      float score = __uint_as_float(key & 0x7FFFFFFFu);
      int k2 = 0;
#pragma unroll
      for (int q = 1; q < 8; ++q) if (n >= c_off[q]) k2 = q;
      int local = n - c_off[k2];
      int w = c_sz[k2], hw = w * w;
      int i2 = local / w, j2 = local % w;
      const float* cp = p.cls[k2] + (size_t)(b * 3) * hw + local;
      float l0 = cp[0], l1 = cp[(size_t)hw], l2 = cp[(size_t)2 * hw];
      float m = l0; int cl = 0;
      if (l1 > m) { m = l1; cl = 1; }
      if (l2 > m) { m = l2; cl = 2; }
      const float* rp = p.reg[k2] + (size_t)(b * 4) * hw + local;
      float r0 = rp[0], r1 = rp[(size_t)hw], r2 = rp[(size_t)2 * hw], r3 = rp[(size_t)3 * hw];
      float st = c_st[k2], rf = c_rf[k2];
      float cx = (float)j2 * st + st * 0.5f;
      float cy = (float)i2 * st + st * 0.5f;
      float x1 = cx - r0 * rf, y1 = cy - r1 * rf;
      float x2 = cx + r2 * rf, y2 = cy + r3 * rf;
      sc[r] = score; cls_s[r] = cl;
      bx1[r] = x1; by1[r] = y1; bx2[r] = x2; by2[r] = y2;
      area[r] = (x2 - x1 + 1.0f) * (y2 - y1 + 1.0f);
      keep[r] = (score >= 0.35f && cl > 0) ? 1 : 0;
    }
  }
  __syncthreads();

  // greedy NMS in a single wave: lane l owns ranks l and l+64; zero barriers
  if (t < 64) {
    int r0 = t, r1 = t + 64;
    float a1x = bx1[r0], a1y = by1[r0], a2x = bx2[r0], a2y = by2[r0], aA = area[r0];
    int k0 = keep[r0];
    bool has1 = (r1 < TOPK);
    float c1x = 0.f, c1y = 0.f, c2x = 0.f, c2y = 0.f, cA = 1.f;
    int k1 = 0;
    if (has1) { c1x = bx1[r1]; c1y = by1[r1]; c2x = bx2[r1]; c2y = by2[r1]; cA = area[r1]; k1 = keep[r1]; }
    for (int i = 0; i < TOPK; ++i) {
      int ol = i & 63, sl = i >> 6;
      int   ki  = __shfl(sl ? k1  : k0,  ol);
      float ix1 = __shfl(sl ? c1x : a1x, ol);
      float iy1 = __shfl(sl ? c1y : a1y, ol);
      float ix2 = __shfl(sl ? c2x : a2x, ol);
      float iy2 = __shfl(sl ? c2y : a2y, ol);
      float iA  = __shfl(sl ? cA  : aA,  ol);
      if (ki) {
        if (k0 && r0 > i) {
          float xmin = fmaxf(ix1, a1x), ymin = fmaxf(iy1, a1y);
          float xmax = fminf(ix2, a2x), ymax = fminf(iy2, a2y);
          float inter = fmaxf(xmax - xmin, 0.f) * fmaxf(ymax - ymin, 0.f);
          float iou = inter / (iA + aA - inter);
          if (iou > 0.5f) k0 = 0;
        }
        if (has1 && k1 && r1 > i) {
          float xmin = fmaxf(ix1, c1x), ymin = fmaxf(iy1, c1y);
          float xmax = fminf(ix2, c2x), ymax = fminf(iy2, c2y);
          float inter = fmaxf(xmax - xmin, 0.f) * fmaxf(ymax - ymin, 0.f);
          float iou = inter / (iA + cA - inter);
          if (iou > 0.5f) k1 = 0;
        }
      }
    }
    keep[r0] = k0;
    if (has1) keep[r1] = k1;
  }
  __syncthreads();

  if (r < TOPK) {
    int o = b * TOPK + r;
    bool kp = keep[r] != 0;
    out[o] = kp ? sc[r] : 0.f;                                  // scores
    out[NBATCH * TOPK + o] = kp ? (float)cls_s[r] : 0.f;        // classes
    float* ob = out + 2 * NBATCH * TOPK + (size_t)o * 4;        // boxes
    ob[0] = kp ? bx1[r] : 0.f;
    ob[1] = kp ? by1[r] : 0.f;
    ob[2] = kp ? bx2[r] : 0.f;
    ob[3] = kp ? by2[r] : 0.f;
    out[6 * NBATCH * TOPK + o] = kp ? 1.f : 0.f;                // keep
  }
}

extern "C" void kernel_launch(void* const* d_in, const int* in_sizes, int n_in,
                              void* d_out, int out_size, void* d_ws, size_t ws_size,
                              hipStream_t stream) {
  Ptrs p;
  // setup_inputs() dict order is INTERLEAVED: cls0, reg0, cls1, reg1, ...
  for (int i = 0; i < 8; ++i) {
    p.cls[i] = (const float*)d_in[2 * i];
    p.reg[i] = (const float*)d_in[2 * i + 1];
  }
  uint32_t* keys    = (uint32_t*)d_ws;                           // 32*65648*4  = 8,402,944 B
  uint16_t* hist    = (uint16_t*)((char*)d_ws + 8402944);        // 32*65*256*2 = 1,064,960 B
  uint32_t* thkey   = (uint32_t*)((char*)d_ws + 9467904);        // 128 B
  uint32_t* counter = (uint32_t*)((char*)d_ws + 9468032);        // 128 B
  unsigned long long* cand =
      (unsigned long long*)((char*)d_ws + 9468160);              // 32*2048*8   = 524,288 B
  float* out = (float*)d_out;                                    // total ws ≈ 10 MB

  k_keys<<<NBATCH * NCHUNK, 256, 0, stream>>>(p, keys, hist);
  k_thresh<<<NBATCH, 256, 0, stream>>>(hist, thkey, counter);
  k_collect<<<NBATCH * NCHUNK, 256, 0, stream>>>(keys, thkey, counter, cand);
  k_final<<<NBATCH, FT, 0, stream>>>(p, counter, cand, out);
}

// Round 12
// 60.255 us; speedup vs baseline: 1.2320x; 1.2320x over previous
//
#include <hip/hip_runtime.h>
#include <stdint.h>

#define N_ANCH 65648
#define NCHUNK 65          // chunks of 1024 anchors
#define CHUNK  1024
#define SEGCAP 1024        // per-chunk segment == chunk size (overflow impossible)
#define CAP    2048        // max candidates gathered in k_final
#define KBASE  0xBE800000u // sortable key of 0.25; fg scores >= 1/3 -> bins in [42,255]
#define NBATCH 32
#define TOPK   100
#define FT     256

struct Ptrs { const float* cls[8]; const float* reg[8]; };

__constant__ int   c_off[9] = {0,25281,50562,56803,63044,64565,64926,65287,65648};
__constant__ int   c_sz[8]  = {159,159,79,79,39,19,19,19};
__constant__ float c_st[8]  = {4.f,4.f,8.f,8.f,16.f,32.f,32.f,32.f};
__constant__ float c_rf[8]  = {27.5f,35.5f,55.5f,71.5f,111.5f,191.5f,255.5f,319.5f};

// sortable key for the masked score of anchor n in batch b; 0 if background.
// EXACT same fp sequence as all passing rounds.
__device__ inline uint32_t anchor_key(const Ptrs& p, int b, int n) {
  int k = 0;
#pragma unroll
  for (int q = 1; q < 8; ++q) if (n >= c_off[q]) k = q;
  int local = n - c_off[k];
  int hw = c_sz[k] * c_sz[k];
  const float* c = p.cls[k] + (size_t)(b * 3) * hw + local;
  float l0 = c[0], l1 = c[(size_t)hw], l2 = c[(size_t)2 * hw];
  float m = l0; int cl = 0;
  if (l1 > m) { m = l1; cl = 1; }
  if (l2 > m) { m = l2; cl = 2; }
  if (cl == 0) return 0u;
  float s = 1.0f / (expf(l0 - m) + expf(l1 - m) + expf(l2 - m));
  return __float_as_uint(s) | 0x80000000u; // positive float -> monotonic uint
}

// K1 (WIDE, 2080 blocks): exact u32 key per anchor (coalesced) + per-chunk u16 hist
__global__ __launch_bounds__(256) void k_keys(Ptrs p, uint32_t* keys, uint16_t* hist) {
  int bid = blockIdx.x;
  int b = bid / NCHUNK, chunk = bid % NCHUNK;
  int t = threadIdx.x;
  __shared__ uint32_t lh[256];
  lh[t] = 0;
  __syncthreads();
  int n_base = chunk * CHUNK;
#pragma unroll
  for (int u = 0; u < 4; ++u) {
    int n = n_base + u * 256 + t;
    if (n < N_ANCH) {
      uint32_t key = anchor_key(p, b, n);
      keys[(size_t)b * N_ANCH + n] = key;
      if (key >= KBASE) atomicAdd(&lh[(key - KBASE) >> 16], 1u);  // LDS only
    }
  }
  __syncthreads();
  hist[((size_t)b * NCHUNK + chunk) * 256 + t] = (uint16_t)lh[t];
}

// K2 (WIDE, 2080 blocks): redundant per-block threshold (L2-warm hist reduce, proven
// ~16 us combined with K1 in round 6); compact own chunk into a PRIVATE per-chunk
// segment. ZERO global atomics anywhere.
__global__ __launch_bounds__(256) void k_collect(const uint32_t* keys, const uint16_t* hist,
                                                 unsigned long long* cand, uint32_t* cnt) {
  int bid = blockIdx.x;
  int b = bid / NCHUNK, chunk = bid % NCHUNK;
  int t = threadIdx.x;
  __shared__ uint32_t tot[256];
  __shared__ int s_thr;
  __shared__ uint32_t s_cnt;
  const uint16_t* hb = hist + (size_t)b * NCHUNK * 256;
  uint32_t v0 = 0, v1 = 0, v2 = 0, v3 = 0;
  int ch = 0;
  for (; ch + 4 <= NCHUNK; ch += 4) {          // 4 accumulators: independent loads
    v0 += hb[(ch + 0) * 256 + t];
    v1 += hb[(ch + 1) * 256 + t];
    v2 += hb[(ch + 2) * 256 + t];
    v3 += hb[(ch + 3) * 256 + t];
  }
  for (; ch < NCHUNK; ++ch) v0 += hb[ch * 256 + t];
  tot[t] = v0 + v1 + v2 + v3;
  if (t == 0) s_cnt = 0;
  __syncthreads();
  for (int d = 1; d < 256; d <<= 1) {          // inclusive suffix sum
    uint32_t add = (t + d < 256) ? tot[t + d] : 0u;
    __syncthreads();
    tot[t] += add;
    __syncthreads();
  }
  uint32_t suf = tot[t], sufn = (t < 255) ? tot[t + 1] : 0u;
  if (suf >= TOPK && sufn < TOPK) s_thr = t;   // exactly one setter
  if (t == 0 && tot[0] < TOPK) s_thr = 0;
  __syncthreads();
  int thr = s_thr; if (thr < 1) thr = 1;       // bin>=1 <=> foreground
  uint32_t thkey = KBASE + ((uint32_t)thr << 16);  // bin(key)>=thr <=> key>=thkey

  int n0 = chunk * CHUNK + t * 4;
  if (n0 < N_ANCH) {                           // full quads (65648 % 4 == 0)
    uint4 kv = *(const uint4*)(keys + (size_t)b * N_ANCH + n0);
    const uint32_t* kp = (const uint32_t*)&kv;
#pragma unroll
    for (int u = 0; u < 4; ++u) {
      uint32_t key = kp[u];
      if (key >= thkey) {
        uint32_t pos = atomicAdd(&s_cnt, 1u);  // LDS; pos < SEGCAP always
        cand[((size_t)b * NCHUNK + chunk) * SEGCAP + pos] =
            ((unsigned long long)key << 32) | (uint32_t)(~(uint32_t)(n0 + u));
      }
    }
  }
  __syncthreads();
  if (t == 0) cnt[(size_t)b * NCHUNK + chunk] = s_cnt;   // pure store
}

// rank-selection with 8-deep batched LDS broadcast reads; s_all zero-padded to
// a multiple of 8 (zeros never outrank real keys).
template<int U>
__device__ inline void rank_select(const unsigned long long* s_all, int c, int c8, int t,
                                   unsigned long long* top) {
  unsigned long long mine[U]; int rk[U];
#pragma unroll
  for (int u = 0; u < U; ++u) {
    int i = t + u * FT;
    mine[u] = (i < c) ? s_all[i] : 0ull;
    rk[u] = 0;
  }
  for (int j = 0; j < c8; j += 8) {
    unsigned long long v0 = s_all[j+0], v1 = s_all[j+1], v2 = s_all[j+2], v3 = s_all[j+3];
    unsigned long long v4 = s_all[j+4], v5 = s_all[j+5], v6 = s_all[j+6], v7 = s_all[j+7];
#pragma unroll
    for (int u = 0; u < U; ++u) {
      rk[u] += (v0 > mine[u]) + (v1 > mine[u]) + (v2 > mine[u]) + (v3 > mine[u])
             + (v4 > mine[u]) + (v5 > mine[u]) + (v6 > mine[u]) + (v7 > mine[u]);
    }
  }
#pragma unroll
  for (int u = 0; u < U; ++u) {
    int i = t + u * FT;
    if (i < c && rk[u] < TOPK) top[rk[u]] = mine[u];   // unique u64s -> unique ranks
  }
}

// K3 (32 blocks): parallel 66-entry scan of chunk counts -> flat gather (one load
// per candidate, binary search on LDS prefix) -> rank-select -> decode -> NMS -> out.
__global__ __launch_bounds__(FT) void k_final(Ptrs p, const uint32_t* cnt,
                                              const unsigned long long* cand, float* out) {
  int b = blockIdx.x, t = threadIdx.x;
  __shared__ uint32_t pref[NCHUNK + 1];        // pref[i] = candidates in chunks < i
  __shared__ unsigned long long s_all[CAP + 8];
  __shared__ unsigned long long top[TOPK];
  __shared__ float bx1[TOPK], by1[TOPK], bx2[TOPK], by2[TOPK], area[TOPK], sc[TOPK];
  __shared__ int cls_s[TOPK], keep[TOPK];

  if (t < NCHUNK) pref[t + 1] = cnt[(size_t)b * NCHUNK + t];
  if (t == 0) pref[0] = 0;
  if (t < TOPK) top[t] = 0ull;
  __syncthreads();
  for (int d = 1; d < NCHUNK + 1; d <<= 1) {   // parallel inclusive scan, 7 steps
    uint32_t v = 0;
    if (t < NCHUNK + 1 && t >= d) v = pref[t - d];
    __syncthreads();
    if (t < NCHUNK + 1) pref[t] += v;
    __syncthreads();
  }
  int c = (int)min(pref[NCHUNK], (uint32_t)CAP);
  int c8 = (c + 7) & ~7;

  // flat gather: thread i finds its chunk by binary search, one global load
  for (int i = t; i < c; i += FT) {
    int lo = 0, hi = NCHUNK - 1;               // find ch: pref[ch] <= i < pref[ch+1]
    while (lo < hi) {
      int mid = (lo + hi + 1) >> 1;
      if ((int)pref[mid] <= i) lo = mid; else hi = mid - 1;
    }
    s_all[i] = cand[((size_t)b * NCHUNK + lo) * SEGCAP + (i - (int)pref[lo])];
  }
  for (int i = c + t; i < c8; i += FT) s_all[i] = 0ull;   // pad
  __syncthreads();

  if      (c <= FT)     rank_select<1>(s_all, c, c8, t, top);
  else if (c <= 2 * FT) rank_select<2>(s_all, c, c8, t, top);
  else if (c <= 4 * FT) rank_select<4>(s_all, c, c8, t, top);
  else                  rank_select<8>(s_all, c, c8, t, top);
  __syncthreads();

  // decode top-100
  int r = t;
  if (r < TOPK) {
    unsigned long long pk = top[r];
    if (pk == 0ull) {
      sc[r] = -1.f; cls_s[r] = 0; keep[r] = 0;
      bx1[r] = by1[r] = bx2[r] = by2[r] = 0.f; area[r] = 1.f;
    } else {
      uint32_t key = (uint32_t)(pk >> 32);
      int n = (int)(~(uint32_t)pk);
      float score = __uint_as_float(key & 0x7FFFFFFFu);
      int k2 = 0;
#pragma unroll
      for (int q = 1; q < 8; ++q) if (n >= c_off[q]) k2 = q;
      int local = n - c_off[k2];
      int w = c_sz[k2], hw = w * w;
      int i2 = local / w, j2 = local % w;
      const float* cp = p.cls[k2] + (size_t)(b * 3) * hw + local;
      float l0 = cp[0], l1 = cp[(size_t)hw], l2 = cp[(size_t)2 * hw];
      float m = l0; int cl = 0;
      if (l1 > m) { m = l1; cl = 1; }
      if (l2 > m) { m = l2; cl = 2; }
      const float* rp = p.reg[k2] + (size_t)(b * 4) * hw + local;
      float r0 = rp[0], r1 = rp[(size_t)hw], r2 = rp[(size_t)2 * hw], r3 = rp[(size_t)3 * hw];
      float st = c_st[k2], rf = c_rf[k2];
      float cx = (float)j2 * st + st * 0.5f;
      float cy = (float)i2 * st + st * 0.5f;
      float x1 = cx - r0 * rf, y1 = cy - r1 * rf;
      float x2 = cx + r2 * rf, y2 = cy + r3 * rf;
      sc[r] = score; cls_s[r] = cl;
      bx1[r] = x1; by1[r] = y1; bx2[r] = x2; by2[r] = y2;
      area[r] = (x2 - x1 + 1.0f) * (y2 - y1 + 1.0f);
      keep[r] = (score >= 0.35f && cl > 0) ? 1 : 0;
    }
  }
  __syncthreads();

  // greedy NMS in a single wave: lane l owns ranks l and l+64; zero barriers
  if (t < 64) {
    int r0 = t, r1 = t + 64;
    float a1x = bx1[r0], a1y = by1[r0], a2x = bx2[r0], a2y = by2[r0], aA = area[r0];
    int k0 = keep[r0];
    bool has1 = (r1 < TOPK);
    float c1x = 0.f, c1y = 0.f, c2x = 0.f, c2y = 0.f, cA = 1.f;
    int k1 = 0;
    if (has1) { c1x = bx1[r1]; c1y = by1[r1]; c2x = bx2[r1]; c2y = by2[r1]; cA = area[r1]; k1 = keep[r1]; }
    for (int i = 0; i < TOPK; ++i) {
      int ol = i & 63, sl = i >> 6;
      int   ki  = __shfl(sl ? k1  : k0,  ol);
      float ix1 = __shfl(sl ? c1x : a1x, ol);
      float iy1 = __shfl(sl ? c1y : a1y, ol);
      float ix2 = __shfl(sl ? c2x : a2x, ol);
      float iy2 = __shfl(sl ? c2y : a2y, ol);
      float iA  = __shfl(sl ? cA  : aA,  ol);
      if (ki) {
        if (k0 && r0 > i) {
          float xmin = fmaxf(ix1, a1x), ymin = fmaxf(iy1, a1y);
          float xmax = fminf(ix2, a2x), ymax = fminf(iy2, a2y);
          float inter = fmaxf(xmax - xmin, 0.f) * fmaxf(ymax - ymin, 0.f);
          float iou = inter / (iA + aA - inter);
          if (iou > 0.5f) k0 = 0;
        }
        if (has1 && k1 && r1 > i) {
          float xmin = fmaxf(ix1, c1x), ymin = fmaxf(iy1, c1y);
          float xmax = fminf(ix2, c2x), ymax = fminf(iy2, c2y);
          float inter = fmaxf(xmax - xmin, 0.f) * fmaxf(ymax - ymin, 0.f);
          float iou = inter / (iA + cA - inter);
          if (iou > 0.5f) k1 = 0;
        }
      }
    }
    keep[r0] = k0;
    if (has1) keep[r1] = k1;
  }
  __syncthreads();

  if (r < TOPK) {
    int o = b * TOPK + r;
    bool kp = keep[r] != 0;
    out[o] = kp ? sc[r] : 0.f;                                  // scores
    out[NBATCH * TOPK + o] = kp ? (float)cls_s[r] : 0.f;        // classes
    float* ob = out + 2 * NBATCH * TOPK + (size_t)o * 4;        // boxes
    ob[0] = kp ? bx1[r] : 0.f;
    ob[1] = kp ? by1[r] : 0.f;
    ob[2] = kp ? bx2[r] : 0.f;
    ob[3] = kp ? by2[r] : 0.f;
    out[6 * NBATCH * TOPK + o] = kp ? 1.f : 0.f;                // keep
  }
}

extern "C" void kernel_launch(void* const* d_in, const int* in_sizes, int n_in,
                              void* d_out, int out_size, void* d_ws, size_t ws_size,
                              hipStream_t stream) {
  Ptrs p;
  // setup_inputs() dict order is INTERLEAVED: cls0, reg0, cls1, reg1, ...
  for (int i = 0; i < 8; ++i) {
    p.cls[i] = (const float*)d_in[2 * i];
    p.reg[i] = (const float*)d_in[2 * i + 1];
  }
  uint32_t* keys = (uint32_t*)d_ws;                              // 32*65648*4   = 8,402,944 B
  uint16_t* hist = (uint16_t*)((char*)d_ws + 8402944);           // 32*65*256*2  = 1,064,960 B
  uint32_t* cnt  = (uint32_t*)((char*)d_ws + 9467904);           // 32*65*4      = 8,320 B
  unsigned long long* cand =
      (unsigned long long*)((char*)d_ws + 9476224);              // 32*65*1024*8 = 17,039,360 B
  float* out = (float*)d_out;                                    // total ws ≈ 26.5 MB

  k_keys<<<NBATCH * NCHUNK, 256, 0, stream>>>(p, keys, hist);
  k_collect<<<NBATCH * NCHUNK, 256, 0, stream>>>(keys, hist, cand, cnt);
  k_final<<<NBATCH, FT, 0, stream>>>(p, cnt, cand, out);
}

// Round 13
// 57.559 us; speedup vs baseline: 1.2897x; 1.0468x over previous
//
#include <hip/hip_runtime.h>
#include <stdint.h>

#define N_ANCH 65648
#define NQ16   (N_ANCH / 16)  // 4103 uint4s of bins per batch (65648 % 16 == 0)
#define NCHUNK 65             // k_bins chunks of 1024 anchors
#define CHUNK  1024
#define CAP    4096           // candidate capacity (LDS)
#define KBASE  0xBE800000u    // sortable key of 0.25; fg scores >= 1/3 -> bins in [42,255]
#define NBATCH 32
#define TOPK   100
#define FT     1024           // k_sel threads

struct Ptrs { const float* cls[8]; const float* reg[8]; };

__constant__ int   c_off[9] = {0,25281,50562,56803,63044,64565,64926,65287,65648};
__constant__ int   c_sz[8]  = {159,159,79,79,39,19,19,19};
__constant__ float c_st[8]  = {4.f,4.f,8.f,8.f,16.f,32.f,32.f,32.f};
__constant__ float c_rf[8]  = {27.5f,35.5f,55.5f,71.5f,111.5f,191.5f,255.5f,319.5f};

// sortable key for the masked score of anchor n in batch b; 0 if background.
// EXACT same fp sequence as all passing rounds.
__device__ inline uint32_t anchor_key(const Ptrs& p, int b, int n) {
  int k = 0;
#pragma unroll
  for (int q = 1; q < 8; ++q) if (n >= c_off[q]) k = q;
  int local = n - c_off[k];
  int hw = c_sz[k] * c_sz[k];
  const float* c = p.cls[k] + (size_t)(b * 3) * hw + local;
  float l0 = c[0], l1 = c[(size_t)hw], l2 = c[(size_t)2 * hw];
  float m = l0; int cl = 0;
  if (l1 > m) { m = l1; cl = 1; }
  if (l2 > m) { m = l2; cl = 2; }
  if (cl == 0) return 0u;
  float s = 1.0f / (expf(l0 - m) + expf(l1 - m) + expf(l2 - m));
  return __float_as_uint(s) | 0x80000000u; // positive float -> monotonic uint
}

// K1 (WIDE, 2080 blocks — proven ~12-14 us shape): u8 bins + per-chunk u16 hist.
// Zero atomics beyond LDS. No keys buffer.
__global__ __launch_bounds__(256) void k_bins(Ptrs p, uint8_t* bins, uint16_t* hist) {
  int bid = blockIdx.x;
  int b = bid / NCHUNK, chunk = bid % NCHUNK;
  int t = threadIdx.x;
  __shared__ uint32_t lh[256];
  lh[t] = 0;
  __syncthreads();
  int n0 = chunk * CHUNK + t * 4;
  if (n0 < N_ANCH) {                           // quads never straddle N_ANCH (65648%4==0)
    uchar4 v; uint8_t* vb = (uint8_t*)&v;
#pragma unroll
    for (int u = 0; u < 4; ++u) {
      uint32_t key = anchor_key(p, b, n0 + u);
      uint8_t bin = key ? (uint8_t)((key - KBASE) >> 16) : (uint8_t)0; // fg in [42,255]
      vb[u] = bin;
      if (bin) atomicAdd(&lh[bin], 1u);        // LDS only, ~680/block
    }
    *(uchar4*)(bins + (size_t)b * N_ANCH + n0) = v;
  }
  __syncthreads();
  hist[((size_t)b * NCHUNK + chunk) * 256 + t] = (uint16_t)lh[t];
}

// rank-selection with 8-deep batched LDS broadcast reads; s_all zero-padded to
// a multiple of 8 (zeros never outrank real keys).
template<int U>
__device__ inline void rank_select(const unsigned long long* s_all, int c, int c8, int t,
                                   unsigned long long* top) {
  unsigned long long mine[U]; int rk[U];
#pragma unroll
  for (int u = 0; u < U; ++u) {
    int i = t + u * FT;
    mine[u] = (i < c) ? s_all[i] : 0ull;
    rk[u] = 0;
  }
  for (int j = 0; j < c8; j += 8) {
    unsigned long long v0 = s_all[j+0], v1 = s_all[j+1], v2 = s_all[j+2], v3 = s_all[j+3];
    unsigned long long v4 = s_all[j+4], v5 = s_all[j+5], v6 = s_all[j+6], v7 = s_all[j+7];
#pragma unroll
    for (int u = 0; u < U; ++u) {
      rk[u] += (v0 > mine[u]) + (v1 > mine[u]) + (v2 > mine[u]) + (v3 > mine[u])
             + (v4 > mine[u]) + (v5 > mine[u]) + (v6 > mine[u]) + (v7 > mine[u]);
    }
  }
#pragma unroll
  for (int u = 0; u < U; ++u) {
    int i = t + u * FT;
    if (i < c && rk[u] < TOPK) top[rk[u]] = mine[u];   // unique u64s -> unique ranks
  }
}

// K2 (32 blocks x 1024): hist reduce -> threshold -> 64KB bin scan -> collect idx
// -> exact keys for ~c candidates only -> rank-select -> decode -> NMS -> out.
__global__ __launch_bounds__(FT) void k_sel(Ptrs p, const uint8_t* bins,
                                            const uint16_t* hist, float* out) {
  int b = blockIdx.x, t = threadIdx.x;
  __shared__ uint32_t part[4][256];
  __shared__ uint32_t tot[256];
  __shared__ int s_idx[CAP];
  __shared__ unsigned long long s_all[CAP + 8];
  __shared__ unsigned long long top[TOPK];
  __shared__ float bx1[TOPK], by1[TOPK], bx2[TOPK], by2[TOPK], area[TOPK], sc[TOPK];
  __shared__ int cls_s[TOPK], keep[TOPK];
  __shared__ uint32_t s_cnt;
  __shared__ int s_thr;

  // ---- threshold from per-chunk hists (r10-proven 4-group reduce) ----
  {
    const uint16_t* hb = hist + (size_t)b * NCHUNK * 256;
    int g = t >> 8, tb = t & 255;
    uint32_t v = 0;
    for (int ch = g; ch < NCHUNK; ch += 4) v += hb[ch * 256 + tb];
    part[g][tb] = v;
    if (t == 0) s_cnt = 0;
    if (t < TOPK) top[t] = 0ull;
    __syncthreads();
    if (t < 256) tot[t] = part[0][t] + part[1][t] + part[2][t] + part[3][t];
    __syncthreads();
    for (int d = 1; d < 256; d <<= 1) {            // inclusive suffix sum
      uint32_t add = 0;
      if (t < 256 && t + d < 256) add = tot[t + d];
      __syncthreads();
      if (t < 256) tot[t] += add;
      __syncthreads();
    }
    if (t < 256) {
      uint32_t suf = tot[t], sufn = (t < 255) ? tot[t + 1] : 0u;
      if (suf >= TOPK && sufn < TOPK) s_thr = t;   // exactly one setter
      if (t == 0 && tot[0] < TOPK) s_thr = 0;
    }
    __syncthreads();
  }
  int thr = s_thr; if (thr < 1) thr = 1;           // bin>=1 <=> foreground

  // ---- scan this batch's 64KB bin array (uint4 = 16 bins, 4 rounds/thread) ----
  {
    const uint4* bp = (const uint4*)(bins + (size_t)b * N_ANCH);
    for (int i = t; i < NQ16; i += FT) {
      uint4 v4 = bp[i];
      uint32_t ws[4] = { v4.x, v4.y, v4.z, v4.w };
#pragma unroll
      for (int w = 0; w < 4; ++w) {
        uint32_t wv = ws[w];
        if (!wv) continue;                          // all-background word
#pragma unroll
        for (int u = 0; u < 4; ++u) {
          int bin = (wv >> (8 * u)) & 0xFF;
          if (bin >= thr) {
            uint32_t q = atomicAdd(&s_cnt, 1u);
            if (q < CAP) s_idx[q] = i * 16 + w * 4 + u;
          }
        }
      }
    }
  }
  __syncthreads();
  int c = (int)min(s_cnt, (uint32_t)CAP);
  int c8 = (c + 7) & ~7;

  // ---- exact keys only for the ~c candidates (cls is L2/L3-warm) ----
  for (int i = t; i < c; i += FT) {
    int n = s_idx[i];
    uint32_t key = anchor_key(p, b, n);
    s_all[i] = ((unsigned long long)key << 32) | (uint32_t)(~(uint32_t)n);
  }
  for (int i = c + t; i < c8; i += FT) s_all[i] = 0ull;   // pad
  __syncthreads();

  if      (c <= FT)     rank_select<1>(s_all, c, c8, t, top);
  else if (c <= 2 * FT) rank_select<2>(s_all, c, c8, t, top);
  else                  rank_select<4>(s_all, c, c8, t, top);
  __syncthreads();

  // ---- decode top-100 ----
  int r = t;
  if (r < TOPK) {
    unsigned long long pk = top[r];
    if (pk == 0ull) {
      sc[r] = -1.f; cls_s[r] = 0; keep[r] = 0;
      bx1[r] = by1[r] = bx2[r] = by2[r] = 0.f; area[r] = 1.f;
    } else {
      uint32_t key = (uint32_t)(pk >> 32);
      int n = (int)(~(uint32_t)pk);
      float score = __uint_as_float(key & 0x7FFFFFFFu);
      int k2 = 0;
#pragma unroll
      for (int q = 1; q < 8; ++q) if (n >= c_off[q]) k2 = q;
      int local = n - c_off[k2];
      int w = c_sz[k2], hw = w * w;
      int i2 = local / w, j2 = local % w;
      const float* cp = p.cls[k2] + (size_t)(b * 3) * hw + local;
      float l0 = cp[0], l1 = cp[(size_t)hw], l2 = cp[(size_t)2 * hw];
      float m = l0; int cl = 0;
      if (l1 > m) { m = l1; cl = 1; }
      if (l2 > m) { m = l2; cl = 2; }
      const float* rp = p.reg[k2] + (size_t)(b * 4) * hw + local;
      float r0 = rp[0], r1 = rp[(size_t)hw], r2 = rp[(size_t)2 * hw], r3 = rp[(size_t)3 * hw];
      float st = c_st[k2], rf = c_rf[k2];
      float cx = (float)j2 * st + st * 0.5f;
      float cy = (float)i2 * st + st * 0.5f;
      float x1 = cx - r0 * rf, y1 = cy - r1 * rf;
      float x2 = cx + r2 * rf, y2 = cy + r3 * rf;
      sc[r] = score; cls_s[r] = cl;
      bx1[r] = x1; by1[r] = y1; bx2[r] = x2; by2[r] = y2;
      area[r] = (x2 - x1 + 1.0f) * (y2 - y1 + 1.0f);
      keep[r] = (score >= 0.35f && cl > 0) ? 1 : 0;
    }
  }
  __syncthreads();

  // ---- greedy NMS in a single wave: lane l owns ranks l and l+64 ----
  if (t < 64) {
    int r0 = t, r1 = t + 64;
    float a1x = bx1[r0], a1y = by1[r0], a2x = bx2[r0], a2y = by2[r0], aA = area[r0];
    int k0 = keep[r0];
    bool has1 = (r1 < TOPK);
    float c1x = 0.f, c1y = 0.f, c2x = 0.f, c2y = 0.f, cA = 1.f;
    int k1 = 0;
    if (has1) { c1x = bx1[r1]; c1y = by1[r1]; c2x = bx2[r1]; c2y = by2[r1]; cA = area[r1]; k1 = keep[r1]; }
    for (int i = 0; i < TOPK; ++i) {
      int ol = i & 63, sl = i >> 6;
      int   ki  = __shfl(sl ? k1  : k0,  ol);
      float ix1 = __shfl(sl ? c1x : a1x, ol);
      float iy1 = __shfl(sl ? c1y : a1y, ol);
      float ix2 = __shfl(sl ? c2x : a2x, ol);
      float iy2 = __shfl(sl ? c2y : a2y, ol);
      float iA  = __shfl(sl ? cA  : aA,  ol);
      if (ki) {
        if (k0 && r0 > i) {
          float xmin = fmaxf(ix1, a1x), ymin = fmaxf(iy1, a1y);
          float xmax = fminf(ix2, a2x), ymax = fminf(iy2, a2y);
          float inter = fmaxf(xmax - xmin, 0.f) * fmaxf(ymax - ymin, 0.f);
          float iou = inter / (iA + aA - inter);
          if (iou > 0.5f) k0 = 0;
        }
        if (has1 && k1 && r1 > i) {
          float xmin = fmaxf(ix1, c1x), ymin = fmaxf(iy1, c1y);
          float xmax = fminf(ix2, c2x), ymax = fminf(iy2, c2y);
          float inter = fmaxf(xmax - xmin, 0.f) * fmaxf(ymax - ymin, 0.f);
          float iou = inter / (iA + cA - inter);
          if (iou > 0.5f) k1 = 0;
        }
      }
    }
    keep[r0] = k0;
    if (has1) keep[r1] = k1;
  }
  __syncthreads();

  if (r < TOPK) {
    int o = b * TOPK + r;
    bool kp = keep[r] != 0;
    out[o] = kp ? sc[r] : 0.f;                                  // scores
    out[NBATCH * TOPK + o] = kp ? (float)cls_s[r] : 0.f;        // classes
    float* ob = out + 2 * NBATCH * TOPK + (size_t)o * 4;        // boxes
    ob[0] = kp ? bx1[r] : 0.f;
    ob[1] = kp ? by1[r] : 0.f;
    ob[2] = kp ? bx2[r] : 0.f;
    ob[3] = kp ? by2[r] : 0.f;
    out[6 * NBATCH * TOPK + o] = kp ? 1.f : 0.f;                // keep
  }
}

extern "C" void kernel_launch(void* const* d_in, const int* in_sizes, int n_in,
                              void* d_out, int out_size, void* d_ws, size_t ws_size,
                              hipStream_t stream) {
  Ptrs p;
  // setup_inputs() dict order is INTERLEAVED: cls0, reg0, cls1, reg1, ...
  for (int i = 0; i < 8; ++i) {
    p.cls[i] = (const float*)d_in[2 * i];
    p.reg[i] = (const float*)d_in[2 * i + 1];
  }
  uint8_t*  bins = (uint8_t*)d_ws;                               // 32*65648    = 2,100,736 B
  uint16_t* hist = (uint16_t*)((char*)d_ws + 2100736);           // 32*65*256*2 = 1,064,960 B
  float* out = (float*)d_out;                                    // total ws ≈ 3.2 MB

  k_bins<<<NBATCH * NCHUNK, 256, 0, stream>>>(p, bins, hist);
  k_sel<<<NBATCH, FT, 0, stream>>>(p, bins, hist, out);
}